// Round 5
// baseline (520.827 us; speedup 1.0000x reference)
//
#include <hip/hip_runtime.h>
#include <math.h>

#define IN_F 64
#define HID 128
#define NCLS 10
#define LSM_BLOCKS 2048

// ---------- degree histogram over targets (1 edge/thread: max outstanding atomics) ----------
__global__ void k_hist(const int* __restrict__ col, int* __restrict__ cnt, int E) {
    int i = blockIdx.x * blockDim.x + threadIdx.x;
    if (i < E) atomicAdd(&cnt[col[i]], 1);
}

// ---------- 3-kernel exclusive scan (cnt -> rowptr), fused dis + pos init ----------
__global__ void k_blocksum(const int* __restrict__ cnt, int* __restrict__ bsum, int n) {
    __shared__ int s[256];
    int i = blockIdx.x * 256 + threadIdx.x;
    s[threadIdx.x] = (i < n) ? cnt[i] : 0;
    __syncthreads();
    for (int off = 128; off > 0; off >>= 1) {
        if (threadIdx.x < off) s[threadIdx.x] += s[threadIdx.x + off];
        __syncthreads();
    }
    if (threadIdx.x == 0) bsum[blockIdx.x] = s[0];
}

__global__ void k_scan_bsum(const int* __restrict__ bsum, int* __restrict__ boff, int nb,
                            int* __restrict__ rowptr, int n, int E) {
    __shared__ int s[512];
    int t = threadIdx.x;
    int v = (t < nb) ? bsum[t] : 0;
    s[t] = v;
    __syncthreads();
    for (int off = 1; off < 512; off <<= 1) {
        int tmp = (t >= off) ? s[t - off] : 0;
        __syncthreads();
        s[t] += tmp;
        __syncthreads();
    }
    if (t < nb) boff[t] = s[t] - v;  // exclusive
    if (t == 0) rowptr[n] = E;
}

__global__ void k_scan_final(const int* __restrict__ cnt, const int* __restrict__ boff,
                             int* __restrict__ rowptr, int* __restrict__ pos,
                             float* __restrict__ dis, int n) {
    __shared__ int s[256];
    int i = blockIdx.x * 256 + threadIdx.x;
    int v = (i < n) ? cnt[i] : 0;
    s[threadIdx.x] = v;
    __syncthreads();
    for (int off = 1; off < 256; off <<= 1) {
        int tmp = (threadIdx.x >= off) ? s[threadIdx.x - off] : 0;
        __syncthreads();
        s[threadIdx.x] += tmp;
        __syncthreads();
    }
    if (i < n) {
        int rp = boff[blockIdx.x] + s[threadIdx.x] - v;  // exclusive
        rowptr[i] = rp;
        pos[i] = rp;                       // running cursor for k_fill
        dis[i] = rsqrtf(1.0f + (float)v);  // +1 self-loop
    }
}

// ---------- CSR fill (1 edge/thread; pos pre-seeded with rowptr => single RMW) ----------
__global__ void k_fill(const int* __restrict__ row, const int* __restrict__ col,
                       int* __restrict__ pos, int* __restrict__ src, int E) {
    int e = blockIdx.x * blockDim.x + threadIdx.x;
    if (e >= E) return;
    int c = col[e];
    int p = atomicAdd(&pos[c], 1);
    src[p] = row[e];
}

// ---------- xs = x * dis[node] (prescale: keeps per-edge gather dependency-free) ----------
__global__ void k_xs(const float* __restrict__ x, const float* __restrict__ dis,
                     float* __restrict__ xs, int n16) {
    int i = blockIdx.x * blockDim.x + threadIdx.x;
    if (i >= n16) return;
    float d = dis[i >> 4];  // 16 float4s per node (64 feats)
    float4 v = ((const float4*)x)[i];
    v.x *= d; v.y *= d; v.z *= d; v.w *= d;
    ((float4*)xs)[i] = v;
}

// ---------- fused gather1 + GEMM1 + bias + relu ----------
// one wave per node; 16 lanes x float4 per row; 4 edge slots/wave, unroll x2.
// WAVE-DECOUPLED: no __syncthreads (hacc[w] is private to wave w) => no
// max-of-4 Poisson-degree straggler tax. LDS sync = wave-local waitcnt
// (pattern proven correct in r2/r3).
__global__ __launch_bounds__(256) void k_l1(const float* __restrict__ xs,
                                            const int* __restrict__ src,
                                            const int* __restrict__ rowptr,
                                            const float* __restrict__ dis,
                                            const float* __restrict__ W1,
                                            const float* __restrict__ b1,
                                            float* __restrict__ h, int n) {
    __shared__ float hacc[4][64];
    int w = threadIdx.x >> 6, lane = threadIdx.x & 63;
    int q = lane >> 4;      // edge slot 0..3
    int f4 = lane & 15;     // float4 chunk within the 64-float row
    int i = blockIdx.x * 4 + w;
    if (i >= n) return;  // wave-uniform; no block barriers in this kernel

    float d = dis[i];
    float4 acc = make_float4(0.f, 0.f, 0.f, 0.f);
    if (q == 0)  // self-loop term counted once (xs already carries d_i)
        acc = ((const float4*)(xs + (size_t)i * IN_F))[f4];
    int end = rowptr[i + 1];
    int e = rowptr[i] + q;
    for (; e + 4 < end; e += 8) {
        int s0 = src[e];
        int s1 = src[e + 4];
        float4 v0 = ((const float4*)(xs + (size_t)s0 * IN_F))[f4];
        float4 v1 = ((const float4*)(xs + (size_t)s1 * IN_F))[f4];
        acc.x += v0.x + v1.x;
        acc.y += v0.y + v1.y;
        acc.z += v0.z + v1.z;
        acc.w += v0.w + v1.w;
    }
    if (e < end) {
        int s = src[e];
        float4 v = ((const float4*)(xs + (size_t)s * IN_F))[f4];
        acc.x += v.x;
        acc.y += v.y;
        acc.z += v.z;
        acc.w += v.w;
    }
    // combine the 4 edge slots: xor butterfly over lane bits 4 and 5
    acc.x += __shfl_xor(acc.x, 16, 64);
    acc.y += __shfl_xor(acc.y, 16, 64);
    acc.z += __shfl_xor(acc.z, 16, 64);
    acc.w += __shfl_xor(acc.w, 16, 64);
    acc.x += __shfl_xor(acc.x, 32, 64);
    acc.y += __shfl_xor(acc.y, 32, 64);
    acc.z += __shfl_xor(acc.z, 32, 64);
    acc.w += __shfl_xor(acc.w, 32, 64);
    if (q == 0) {
        acc.x *= d; acc.y *= d; acc.z *= d; acc.w *= d;
        ((float4*)hacc[w])[f4] = acc;
    }
    // wave-local LDS visibility: writers and readers are the same wave
    asm volatile("s_waitcnt lgkmcnt(0)" ::: "memory");

    float h0 = b1[lane], h1 = b1[lane + 64];
#pragma unroll
    for (int k4 = 0; k4 < 16; ++k4) {
        float4 a = ((const float4*)hacc[w])[k4];  // LDS b128 broadcast
        const float* wp = W1 + (k4 * 4) * HID + lane;
        h0 = fmaf(a.x, wp[0 * HID], h0);      h1 = fmaf(a.x, wp[0 * HID + 64], h1);
        h0 = fmaf(a.y, wp[1 * HID], h0);      h1 = fmaf(a.y, wp[1 * HID + 64], h1);
        h0 = fmaf(a.z, wp[2 * HID], h0);      h1 = fmaf(a.z, wp[2 * HID + 64], h1);
        h0 = fmaf(a.w, wp[3 * HID], h0);      h1 = fmaf(a.w, wp[3 * HID + 64], h1);
    }
    h[(size_t)i * HID + lane] = fmaxf(h0, 0.f);
    h[(size_t)i * HID + lane + 64] = fmaxf(h1, 0.f);
}

// ---------- h2p[i,c] = dis[i] * sum_k h[i,k] W2[k,c]  (padded 16-float rows) ----------
__global__ void k_h2s(const float* __restrict__ h, const float* __restrict__ W2,
                      const float* __restrict__ dis, float* __restrict__ h2p, int n) {
    int idx = blockIdx.x * blockDim.x + threadIdx.x;
    if (idx >= n * 16) return;
    int node = idx >> 4;
    int c = idx & 15;
    float r = 0.f;
    if (c < NCLS) {
        const float* hr = h + (size_t)node * HID;
        float acc = 0.f;
#pragma unroll
        for (int k = 0; k < HID; k += 4) {
            float4 hv = *(const float4*)(hr + k);
            acc = fmaf(hv.x, W2[(k + 0) * NCLS + c], acc);
            acc = fmaf(hv.y, W2[(k + 1) * NCLS + c], acc);
            acc = fmaf(hv.z, W2[(k + 2) * NCLS + c], acc);
            acc = fmaf(hv.w, W2[(k + 3) * NCLS + c], acc);
        }
        r = acc * dis[node];
    }
    h2p[idx] = r;
}

// ---------- fused gather2 + b2 + log-softmax + per-block partial reduce ----------
// wave per node (grid-stride); 4 slots x 16 lanes; rows are padded 64B => coalesced
__global__ __launch_bounds__(256) void k_lsm2(const float* __restrict__ h2p,
                                              const int* __restrict__ src,
                                              const int* __restrict__ rowptr,
                                              const float* __restrict__ dis,
                                              const float* __restrict__ b2,
                                              float* __restrict__ partial, int n) {
    __shared__ float sred[4][16];
    int w = threadIdx.x >> 6, lane = threadIdx.x & 63;
    int q = lane >> 4, c = lane & 15;
    int gw = blockIdx.x * 4 + w;
    int nw = gridDim.x * 4;
    float b2c = (c < NCLS) ? b2[c] : 0.f;
    float bsum = 0.f;
    for (int i = gw; i < n; i += nw) {
        int beg = rowptr[i], end = rowptr[i + 1];
        float acc = (q == 0) ? h2p[(size_t)i * 16 + c] : 0.f;  // self
        int e = beg + q;
        for (; e + 12 < end; e += 16) {
            int s0 = src[e], s1 = src[e + 4], s2 = src[e + 8], s3 = src[e + 12];
            float v0 = h2p[(size_t)s0 * 16 + c];
            float v1 = h2p[(size_t)s1 * 16 + c];
            float v2 = h2p[(size_t)s2 * 16 + c];
            float v3 = h2p[(size_t)s3 * 16 + c];
            acc += (v0 + v1) + (v2 + v3);
        }
        for (; e + 4 < end; e += 8) {
            int s0 = src[e], s1 = src[e + 4];
            acc += h2p[(size_t)s0 * 16 + c] + h2p[(size_t)s1 * 16 + c];
        }
        if (e < end) acc += h2p[(size_t)src[e] * 16 + c];
        // combine slots (all lanes end with the full sum)
        acc += __shfl_xor(acc, 16);
        acc += __shfl_xor(acc, 32);
        float vv = b2c + dis[i] * acc;
        // softmax over c=0..9 within each 16-lane group
        float m = (c < NCLS) ? vv : -1e30f;
        m = fmaxf(m, __shfl_xor(m, 1));
        m = fmaxf(m, __shfl_xor(m, 2));
        m = fmaxf(m, __shfl_xor(m, 4));
        m = fmaxf(m, __shfl_xor(m, 8));
        float ex = (c < NCLS) ? __expf(vv - m) : 0.f;
        float se = ex;
        se += __shfl_xor(se, 1);
        se += __shfl_xor(se, 2);
        se += __shfl_xor(se, 4);
        se += __shfl_xor(se, 8);
        float lse = m + __logf(se);
        if (q == 0 && c < NCLS) bsum += vv - lse;
    }
    if (q == 0) sred[w][c] = bsum;  // c>=10 lanes wrote 0
    __syncthreads();
    if (threadIdx.x < 16) {
        float t = sred[0][threadIdx.x] + sred[1][threadIdx.x] +
                  sred[2][threadIdx.x] + sred[3][threadIdx.x];
        partial[blockIdx.x * 16 + threadIdx.x] = t;
    }
}

// ---------- final reduction of per-block partials ----------
__global__ void k_final(const float* __restrict__ partial, float* __restrict__ out,
                        int nb16, float inv_n) {
    __shared__ float sred[256];
    float s = 0.f;
    for (int j = threadIdx.x; j < nb16; j += 256) s += partial[j];  // j&15 constant per thread
    sred[threadIdx.x] = s;
    __syncthreads();
    if (threadIdx.x < 16) {
        float t = 0.f;
        for (int r = threadIdx.x; r < 256; r += 16) t += sred[r];
        if (threadIdx.x < NCLS) out[threadIdx.x] = t * inv_n;
    }
}

extern "C" void kernel_launch(void* const* d_in, const int* in_sizes, int n_in,
                              void* d_out, int out_size, void* d_ws, size_t ws_size,
                              hipStream_t stream) {
    const float* x = (const float*)d_in[0];
    const int* eidx = (const int*)d_in[1];
    const float* W1 = (const float*)d_in[2];
    const float* b1 = (const float*)d_in[3];
    const float* W2 = (const float*)d_in[4];
    const float* b2 = (const float*)d_in[5];
    float* out = (float*)d_out;

    const int N = in_sizes[0] / IN_F;  // 100000
    const int E = in_sizes[1] / 2;     // 1600000
    const int* row = eidx;             // sources
    const int* col = eidx + E;         // targets

    const int NB = (N + 255) / 256;  // scan blocks (391 <= 512)

    // workspace layout (4-byte words, 1024-word aligned)
    size_t o = 0;
    auto alloc = [&](size_t words) {
        size_t r = o;
        o += (words + 1023) & ~(size_t)1023;
        return r;
    };
    float* ws = (float*)d_ws;
    float* dis = ws + alloc(N);
    float* xs = ws + alloc((size_t)N * IN_F);
    float* h = ws + alloc((size_t)N * HID);
    float* h2p = ws + alloc((size_t)N * 16);
    float* partial = ws + alloc(LSM_BLOCKS * 16);
    int* src = (int*)(ws + alloc(E));
    int* rowptr = (int*)(ws + alloc(N + 1));
    int* cnt = (int*)(ws + alloc(N));
    int* pos = (int*)(ws + alloc(N));
    int* bsum = (int*)(ws + alloc(1024));
    int* boff = (int*)(ws + alloc(1024));

    const int B = 256;

    // ---- CSR build + degrees (dis, pos fused into scan) ----
    hipMemsetAsync(cnt, 0, (size_t)N * sizeof(int), stream);
    k_hist<<<(E + B - 1) / B, B, 0, stream>>>(col, cnt, E);
    k_blocksum<<<NB, 256, 0, stream>>>(cnt, bsum, N);
    k_scan_bsum<<<1, 512, 0, stream>>>(bsum, boff, NB, rowptr, N, E);
    k_scan_final<<<NB, 256, 0, stream>>>(cnt, boff, rowptr, pos, dis, N);
    k_fill<<<(E + B - 1) / B, B, 0, stream>>>(row, col, pos, src, E);

    // ---- prescale + layer 1 (aggregate, then transform) ----
    k_xs<<<(N * 16 + B - 1) / B, B, 0, stream>>>(x, dis, xs, N * 16);
    k_l1<<<(N + 3) / 4, 256, 0, stream>>>(xs, src, rowptr, dis, W1, b1, h, N);

    // ---- layer 2 transform (pre-scaled padded messages) ----
    k_h2s<<<(N * 16 + B - 1) / B, B, 0, stream>>>(h, W2, dis, h2p, N);

    // ---- layer 2 aggregate + log-softmax + partial reduce ----
    k_lsm2<<<LSM_BLOCKS, 256, 0, stream>>>(h2p, src, rowptr, dis, b2, partial, N);
    k_final<<<1, 256, 0, stream>>>(partial, out, LSM_BLOCKS * 16, 1.0f / (float)N);
}

// Round 6
// 497.940 us; speedup vs baseline: 1.0460x; 1.0460x over previous
//
#include <hip/hip_runtime.h>
#include <hip/hip_fp16.h>
#include <math.h>

#define IN_F 64
#define HID 128
#define NCLS 10
#define LSM_BLOCKS 2048

// ---------- degree histogram over targets (1 edge/thread: max outstanding atomics) ----------
__global__ void k_hist(const int* __restrict__ col, int* __restrict__ cnt, int E) {
    int i = blockIdx.x * blockDim.x + threadIdx.x;
    if (i < E) atomicAdd(&cnt[col[i]], 1);
}

// ---------- 3-kernel exclusive scan (cnt -> rowptr), fused dis + pos init ----------
__global__ void k_blocksum(const int* __restrict__ cnt, int* __restrict__ bsum, int n) {
    __shared__ int s[256];
    int i = blockIdx.x * 256 + threadIdx.x;
    s[threadIdx.x] = (i < n) ? cnt[i] : 0;
    __syncthreads();
    for (int off = 128; off > 0; off >>= 1) {
        if (threadIdx.x < off) s[threadIdx.x] += s[threadIdx.x + off];
        __syncthreads();
    }
    if (threadIdx.x == 0) bsum[blockIdx.x] = s[0];
}

__global__ void k_scan_bsum(const int* __restrict__ bsum, int* __restrict__ boff, int nb,
                            int* __restrict__ rowptr, int n, int E) {
    __shared__ int s[512];
    int t = threadIdx.x;
    int v = (t < nb) ? bsum[t] : 0;
    s[t] = v;
    __syncthreads();
    for (int off = 1; off < 512; off <<= 1) {
        int tmp = (t >= off) ? s[t - off] : 0;
        __syncthreads();
        s[t] += tmp;
        __syncthreads();
    }
    if (t < nb) boff[t] = s[t] - v;  // exclusive
    if (t == 0) rowptr[n] = E;
}

__global__ void k_scan_final(const int* __restrict__ cnt, const int* __restrict__ boff,
                             int* __restrict__ rowptr, int* __restrict__ pos,
                             float* __restrict__ dis, int n) {
    __shared__ int s[256];
    int i = blockIdx.x * 256 + threadIdx.x;
    int v = (i < n) ? cnt[i] : 0;
    s[threadIdx.x] = v;
    __syncthreads();
    for (int off = 1; off < 256; off <<= 1) {
        int tmp = (threadIdx.x >= off) ? s[threadIdx.x - off] : 0;
        __syncthreads();
        s[threadIdx.x] += tmp;
        __syncthreads();
    }
    if (i < n) {
        int rp = boff[blockIdx.x] + s[threadIdx.x] - v;  // exclusive
        rowptr[i] = rp;
        pos[i] = rp;                       // running cursor for k_fill
        dis[i] = rsqrtf(1.0f + (float)v);  // +1 self-loop
    }
}

// ---------- CSR fill (1 edge/thread; pos pre-seeded with rowptr => single RMW) ----------
__global__ void k_fill(const int* __restrict__ row, const int* __restrict__ col,
                       int* __restrict__ pos, int* __restrict__ src, int E) {
    int e = blockIdx.x * blockDim.x + threadIdx.x;
    if (e >= E) return;
    int c = col[e];
    int p = atomicAdd(&pos[c], 1);
    src[p] = row[e];
}

// ---------- xs = fp16(x * dis[node])  (128B rows: halves gather bytes) ----------
__global__ void k_xs(const float* __restrict__ x, const float* __restrict__ dis,
                     __half* __restrict__ xs, int n8) {
    int i = blockIdx.x * blockDim.x + threadIdx.x;
    if (i >= n8) return;
    float d = dis[i >> 3];  // 8 threads per 64-float row
    float4 a = ((const float4*)x)[i * 2];
    float4 b = ((const float4*)x)[i * 2 + 1];
    __half2 p0 = __floats2half2_rn(a.x * d, a.y * d);
    __half2 p1 = __floats2half2_rn(a.z * d, a.w * d);
    __half2 p2 = __floats2half2_rn(b.x * d, b.y * d);
    __half2 p3 = __floats2half2_rn(b.z * d, b.w * d);
    uint4 wv;
    wv.x = *(const unsigned*)&p0;
    wv.y = *(const unsigned*)&p1;
    wv.z = *(const unsigned*)&p2;
    wv.w = *(const unsigned*)&p3;
    ((uint4*)xs)[i] = wv;  // 16B store (8 halves)
}

// ---------- fused gather1 + GEMM1 + bias + relu ----------
// one wave per node; 16 lanes x 8B (4 halves) per 128B row; 4 edge slots/wave,
// unroll x2 => 8 rows in flight. f32 accumulate. Wave-decoupled (no barrier).
__global__ __launch_bounds__(256) void k_l1(const __half* __restrict__ xs,
                                            const int* __restrict__ src,
                                            const int* __restrict__ rowptr,
                                            const float* __restrict__ dis,
                                            const float* __restrict__ W1,
                                            const float* __restrict__ b1,
                                            __half* __restrict__ h, int n) {
    __shared__ float hacc[4][64];
    int w = threadIdx.x >> 6, lane = threadIdx.x & 63;
    int q = lane >> 4;      // edge slot 0..3
    int f4 = lane & 15;     // 4-half chunk within the 64-half row
    int i = blockIdx.x * 4 + w;
    if (i >= n) return;  // wave-uniform; no block barriers in this kernel

    float d = dis[i];
    float4 acc = make_float4(0.f, 0.f, 0.f, 0.f);
    if (q == 0) {  // self-loop term counted once (xs already carries d_i)
        float2 r = ((const float2*)(xs + (size_t)i * IN_F))[f4];
        __half2 a0 = *(__half2*)&r.x, a1 = *(__half2*)&r.y;
        float2 f0 = __half22float2(a0), f1 = __half22float2(a1);
        acc.x = f0.x; acc.y = f0.y; acc.z = f1.x; acc.w = f1.y;
    }
    int end = rowptr[i + 1];
    int e = rowptr[i] + q;
    for (; e + 4 < end; e += 8) {
        int s0 = src[e];
        int s1 = src[e + 4];
        float2 r0 = ((const float2*)(xs + (size_t)s0 * IN_F))[f4];  // 8B = 4 halves
        float2 r1 = ((const float2*)(xs + (size_t)s1 * IN_F))[f4];
        __half2 a0 = *(__half2*)&r0.x, a1 = *(__half2*)&r0.y;
        __half2 b0 = *(__half2*)&r1.x, b1 = *(__half2*)&r1.y;
        float2 f00 = __half22float2(a0), f01 = __half22float2(a1);
        float2 f10 = __half22float2(b0), f11 = __half22float2(b1);
        acc.x += f00.x + f10.x;
        acc.y += f00.y + f10.y;
        acc.z += f01.x + f11.x;
        acc.w += f01.y + f11.y;
    }
    if (e < end) {
        int s = src[e];
        float2 r0 = ((const float2*)(xs + (size_t)s * IN_F))[f4];
        __half2 a0 = *(__half2*)&r0.x, a1 = *(__half2*)&r0.y;
        float2 f0 = __half22float2(a0), f1 = __half22float2(a1);
        acc.x += f0.x;
        acc.y += f0.y;
        acc.z += f1.x;
        acc.w += f1.y;
    }
    // combine the 4 edge slots: xor butterfly over lane bits 4 and 5
    acc.x += __shfl_xor(acc.x, 16, 64);
    acc.y += __shfl_xor(acc.y, 16, 64);
    acc.z += __shfl_xor(acc.z, 16, 64);
    acc.w += __shfl_xor(acc.w, 16, 64);
    acc.x += __shfl_xor(acc.x, 32, 64);
    acc.y += __shfl_xor(acc.y, 32, 64);
    acc.z += __shfl_xor(acc.z, 32, 64);
    acc.w += __shfl_xor(acc.w, 32, 64);
    if (q == 0) {
        acc.x *= d; acc.y *= d; acc.z *= d; acc.w *= d;
        ((float4*)hacc[w])[f4] = acc;
    }
    // wave-local LDS visibility: writers and readers are the same wave
    asm volatile("s_waitcnt lgkmcnt(0)" ::: "memory");

    float h0 = b1[lane], h1 = b1[lane + 64];
#pragma unroll
    for (int k4 = 0; k4 < 16; ++k4) {
        float4 a = ((const float4*)hacc[w])[k4];  // LDS b128 broadcast
        const float* wp = W1 + (k4 * 4) * HID + lane;
        h0 = fmaf(a.x, wp[0 * HID], h0);      h1 = fmaf(a.x, wp[0 * HID + 64], h1);
        h0 = fmaf(a.y, wp[1 * HID], h0);      h1 = fmaf(a.y, wp[1 * HID + 64], h1);
        h0 = fmaf(a.z, wp[2 * HID], h0);      h1 = fmaf(a.z, wp[2 * HID + 64], h1);
        h0 = fmaf(a.w, wp[3 * HID], h0);      h1 = fmaf(a.w, wp[3 * HID + 64], h1);
    }
    __half* hp = h + (size_t)i * HID;
    hp[lane] = __float2half_rn(fmaxf(h0, 0.f));
    hp[lane + 64] = __float2half_rn(fmaxf(h1, 0.f));
}

// ---------- h2p[i,c] = fp16(dis[i] * sum_k h[i,k] W2[k,c])  (32B padded rows) ----------
__global__ void k_h2s(const __half* __restrict__ h, const float* __restrict__ W2,
                      const float* __restrict__ dis, __half* __restrict__ h2p, int n) {
    int idx = blockIdx.x * blockDim.x + threadIdx.x;
    if (idx >= n * 16) return;
    int node = idx >> 4;
    int c = idx & 15;
    float r = 0.f;
    if (c < NCLS) {
        const __half* hr = h + (size_t)node * HID;
        float acc = 0.f;
#pragma unroll
        for (int k = 0; k < HID; k += 8) {
            float4 raw = *(const float4*)(hr + k);  // 8 halves
            __half2 q0 = *(__half2*)&raw.x, q1 = *(__half2*)&raw.y;
            __half2 q2 = *(__half2*)&raw.z, q3 = *(__half2*)&raw.w;
            float2 g0 = __half22float2(q0), g1 = __half22float2(q1);
            float2 g2 = __half22float2(q2), g3 = __half22float2(q3);
            acc = fmaf(g0.x, W2[(k + 0) * NCLS + c], acc);
            acc = fmaf(g0.y, W2[(k + 1) * NCLS + c], acc);
            acc = fmaf(g1.x, W2[(k + 2) * NCLS + c], acc);
            acc = fmaf(g1.y, W2[(k + 3) * NCLS + c], acc);
            acc = fmaf(g2.x, W2[(k + 4) * NCLS + c], acc);
            acc = fmaf(g2.y, W2[(k + 5) * NCLS + c], acc);
            acc = fmaf(g3.x, W2[(k + 6) * NCLS + c], acc);
            acc = fmaf(g3.y, W2[(k + 7) * NCLS + c], acc);
        }
        r = acc * dis[node];
    }
    h2p[idx] = __float2half_rn(r);
}

// ---------- fused gather2 + b2 + log-softmax + per-block partial reduce ----------
// wave per node (grid-stride); 4 slots x 16 lanes x 2B; h2p total = 3.2MB => L2-resident
__global__ __launch_bounds__(256) void k_lsm2(const __half* __restrict__ h2p,
                                              const int* __restrict__ src,
                                              const int* __restrict__ rowptr,
                                              const float* __restrict__ dis,
                                              const float* __restrict__ b2,
                                              float* __restrict__ partial, int n) {
    __shared__ float sred[4][16];
    int w = threadIdx.x >> 6, lane = threadIdx.x & 63;
    int q = lane >> 4, c = lane & 15;
    int gw = blockIdx.x * 4 + w;
    int nw = gridDim.x * 4;
    float b2c = (c < NCLS) ? b2[c] : 0.f;
    float bsum = 0.f;
    for (int i = gw; i < n; i += nw) {
        int beg = rowptr[i], end = rowptr[i + 1];
        float acc = (q == 0) ? __half2float(h2p[(size_t)i * 16 + c]) : 0.f;  // self
        int e = beg + q;
        for (; e + 12 < end; e += 16) {
            int s0 = src[e], s1 = src[e + 4], s2 = src[e + 8], s3 = src[e + 12];
            float v0 = __half2float(h2p[(size_t)s0 * 16 + c]);
            float v1 = __half2float(h2p[(size_t)s1 * 16 + c]);
            float v2 = __half2float(h2p[(size_t)s2 * 16 + c]);
            float v3 = __half2float(h2p[(size_t)s3 * 16 + c]);
            acc += (v0 + v1) + (v2 + v3);
        }
        for (; e + 4 < end; e += 8) {
            int s0 = src[e], s1 = src[e + 4];
            acc += __half2float(h2p[(size_t)s0 * 16 + c]) +
                   __half2float(h2p[(size_t)s1 * 16 + c]);
        }
        if (e < end) acc += __half2float(h2p[(size_t)src[e] * 16 + c]);
        // combine slots (all lanes end with the full sum)
        acc += __shfl_xor(acc, 16);
        acc += __shfl_xor(acc, 32);
        float vv = b2c + dis[i] * acc;
        // softmax over c=0..9 within each 16-lane group
        float m = (c < NCLS) ? vv : -1e30f;
        m = fmaxf(m, __shfl_xor(m, 1));
        m = fmaxf(m, __shfl_xor(m, 2));
        m = fmaxf(m, __shfl_xor(m, 4));
        m = fmaxf(m, __shfl_xor(m, 8));
        float ex = (c < NCLS) ? __expf(vv - m) : 0.f;
        float se = ex;
        se += __shfl_xor(se, 1);
        se += __shfl_xor(se, 2);
        se += __shfl_xor(se, 4);
        se += __shfl_xor(se, 8);
        float lse = m + __logf(se);
        if (q == 0 && c < NCLS) bsum += vv - lse;
    }
    if (q == 0) sred[w][c] = bsum;  // c>=10 lanes wrote 0
    __syncthreads();
    if (threadIdx.x < 16) {
        float t = sred[0][threadIdx.x] + sred[1][threadIdx.x] +
                  sred[2][threadIdx.x] + sred[3][threadIdx.x];
        partial[blockIdx.x * 16 + threadIdx.x] = t;
    }
}

// ---------- final reduction of per-block partials ----------
__global__ void k_final(const float* __restrict__ partial, float* __restrict__ out,
                        int nb16, float inv_n) {
    __shared__ float sred[256];
    float s = 0.f;
    for (int j = threadIdx.x; j < nb16; j += 256) s += partial[j];  // j&15 constant per thread
    sred[threadIdx.x] = s;
    __syncthreads();
    if (threadIdx.x < 16) {
        float t = 0.f;
        for (int r = threadIdx.x; r < 256; r += 16) t += sred[r];
        if (threadIdx.x < NCLS) out[threadIdx.x] = t * inv_n;
    }
}

extern "C" void kernel_launch(void* const* d_in, const int* in_sizes, int n_in,
                              void* d_out, int out_size, void* d_ws, size_t ws_size,
                              hipStream_t stream) {
    const float* x = (const float*)d_in[0];
    const int* eidx = (const int*)d_in[1];
    const float* W1 = (const float*)d_in[2];
    const float* b1 = (const float*)d_in[3];
    const float* W2 = (const float*)d_in[4];
    const float* b2 = (const float*)d_in[5];
    float* out = (float*)d_out;

    const int N = in_sizes[0] / IN_F;  // 100000
    const int E = in_sizes[1] / 2;     // 1600000
    const int* row = eidx;             // sources
    const int* col = eidx + E;         // targets

    const int NB = (N + 255) / 256;  // scan blocks (391 <= 512)

    // workspace layout (4-byte words, 1024-word aligned)
    size_t o = 0;
    auto alloc = [&](size_t words) {
        size_t r = o;
        o += (words + 1023) & ~(size_t)1023;
        return r;
    };
    float* ws = (float*)d_ws;
    float* dis = ws + alloc(N);
    __half* xs = (__half*)(ws + alloc((size_t)N * IN_F / 2));
    __half* h = (__half*)(ws + alloc((size_t)N * HID / 2));
    __half* h2p = (__half*)(ws + alloc((size_t)N * 8));
    float* partial = ws + alloc(LSM_BLOCKS * 16);
    int* src = (int*)(ws + alloc(E));
    int* rowptr = (int*)(ws + alloc(N + 1));
    int* cnt = (int*)(ws + alloc(N));
    int* pos = (int*)(ws + alloc(N));
    int* bsum = (int*)(ws + alloc(1024));
    int* boff = (int*)(ws + alloc(1024));

    const int B = 256;

    // ---- CSR build + degrees (dis, pos fused into scan) ----
    hipMemsetAsync(cnt, 0, (size_t)N * sizeof(int), stream);
    k_hist<<<(E + B - 1) / B, B, 0, stream>>>(col, cnt, E);
    k_blocksum<<<NB, 256, 0, stream>>>(cnt, bsum, N);
    k_scan_bsum<<<1, 512, 0, stream>>>(bsum, boff, NB, rowptr, N, E);
    k_scan_final<<<NB, 256, 0, stream>>>(cnt, boff, rowptr, pos, dis, N);
    k_fill<<<(E + B - 1) / B, B, 0, stream>>>(row, col, pos, src, E);

    // ---- prescale (fp16) + layer 1 (aggregate, then transform) ----
    k_xs<<<(N * 8 + B - 1) / B, B, 0, stream>>>(x, dis, xs, N * 8);
    k_l1<<<(N + 3) / 4, 256, 0, stream>>>(xs, src, rowptr, dis, W1, b1, h, N);

    // ---- layer 2 transform (pre-scaled padded fp16 messages) ----
    k_h2s<<<(N * 16 + B - 1) / B, B, 0, stream>>>(h, W2, dis, h2p, N);

    // ---- layer 2 aggregate + log-softmax + partial reduce ----
    k_lsm2<<<LSM_BLOCKS, 256, 0, stream>>>(h2p, src, rowptr, dis, b2, partial, N);
    k_final<<<1, 256, 0, stream>>>(partial, out, LSM_BLOCKS * 16, 1.0f / (float)N);
}